// Round 1
// 496.729 us; speedup vs baseline: 1.1169x; 1.1169x over previous
//
#include <hip/hip_runtime.h>
#include <hip/hip_bf16.h>

#define NN 528
#define NP (NN*NN)
#define IMG 512
#define IMGP (IMG*IMG)
#define PAD 8
#define KH 17
#define KT (KH*KH)
#define NF 24
#define RK 5
#define RKT (RK*RK)
#define ND 4
// per-channel border pixel counts
#define TOPB (17*NN)
#define ROWB (2*TOPB)
#define SIDEB (494*34)
#define BORD (ROWB + SIDEB)     // 34748

static __device__ __forceinline__ float ldx(const void* p, long i, int bf) {
    if (bf) return __bfloat162float(((const __hip_bfloat16*)p)[i]);
    return ((const float*)p)[i];
}

// mirror-of-circular map: padded-domain offset m in [-16, 528) -> source index in [0,512)
static __device__ __forceinline__ int gmap(int m) {
    if (m < -8)  return 495 - m;   // -16..-9  -> 511..504
    if (m < 0)   return -m - 1;    // -8..-1   -> 7..0
    if (m < 512) return m;
    if (m < 520) return 1023 - m;  // 512..519 -> 511..504
    return 527 - m;                // 520..527 -> 7..0
}

__global__ void detect_k(const void* pimg, int nimg, const void* pbk, int nbk,
                         const void* pwcw, int nwcw, const void* pws, int nws,
                         const float* c4a, const float* c4b,
                         int* __restrict__ flags,
                         float* __restrict__ alpha_ws, float* __restrict__ wgt_ws) {
    int t = threadIdx.x;
    const void* ps[4] = {pimg, pbk, pwcw, pws};
    int ns[4] = {nimg, nbk, nwcw, nws};
    if (t < 4) {
        const unsigned short* q = (const unsigned short*)ps[t];
        int n = ns[t];
        int K = n < 512 ? n : 512;
        int cnt = 0, pass = 0;
        for (int i = 0; i < K; i += 2) {
            int e = (q[i] >> 7) & 0xFF;
            pass += (e >= 100 && e <= 140);
            cnt++;
        }
        flags[t] = (pass * 10 >= cnt * 8) ? 1 : 0;
    }
    if (t == 7) {
        const float* A = (c4a[0] < 0.f) ? c4a : c4b;
        const float* W = (c4a[0] < 0.f) ? c4b : c4a;
        for (int i = 0; i < ND; ++i) { alpha_ws[i] = A[i]; wgt_ws[i] = W[i]; }
    }
}

__global__ void twinit_k(float2* __restrict__ twN) {
    int i = blockIdx.x * blockDim.x + threadIdx.x;
    if (i < NN) {
        double th = -6.283185307179586476925287 * (double)i / (double)NN;
        twN[i] = make_float2((float)cos(th), (float)sin(th));
    }
}

__global__ void wnorm_k(const void* __restrict__ wcw, const void* __restrict__ wscale,
                        const int* __restrict__ flags, float* __restrict__ wout) {
    int f = threadIdx.x;
    if (f >= NF) return;
    int bfw = flags[2], bfs = flags[3];
    float v[RKT];
    float mean = 0.f;
    for (int i = 0; i < RKT; ++i) { v[i] = ldx(wcw, f*RKT+i, bfw); mean += v[i]; }
    mean *= (1.f/(float)RKT);
    float ss = 0.f;
    for (int i = 0; i < RKT; ++i) { v[i] -= mean; ss += v[i]*v[i]; }
    float sc = ldx(wscale, f, bfs) / sqrtf(ss);
    for (int i = 0; i < RKT; ++i) wout[f*RKT+i] = v[i]*sc;
}

__global__ void prep_k(const void* __restrict__ blurKernel, const int* __restrict__ flags,
                       float* __restrict__ psf_all, float* __restrict__ A0_all,
                       float* __restrict__ A1_all) {
    int b = blockIdx.x, t = threadIdx.x;
    int bf = flags[1];
    __shared__ float psf[KT];
    __shared__ float q0[KH], q1[KH], ac0[KH], ac1[KH];
    for (int i = t; i < KT; i += 64) {
        float v = ldx(blurKernel, b*KT + i, bf);
        psf[i] = v;
        psf_all[b*KT + i] = v;
    }
    __syncthreads();
    if (t < KH) {
        float s0 = 0.f, s1 = 0.f;
        for (int k = 0; k < KH; ++k) { s0 += psf[t*KH + k]; s1 += psf[k*KH + t]; }
        q0[t] = s0; q1[t] = s1;
    }
    __syncthreads();
    if (t < KH) {
        float a0 = 0.f, a1 = 0.f;
        for (int m = 0; m + t < KH; ++m) { a0 += q0[m]*q0[m+t]; a1 += q1[m]*q1[m+t]; }
        ac0[t] = a0; ac1[t] = a1;
    }
    __syncthreads();
    for (int r = t; r < NN; r += 64) {
        int lag = min(r, (NN-1) - r);
        float b0 = (lag <= KH-1) ? ac0[lag]/ac0[0] : 0.f;
        float b1 = (lag <= KH-1) ? ac1[lag]/ac1[0] : 0.f;
        A0_all[b*NN + r] = 1.f - b0;
        A1_all[b*NN + r] = 1.f - b1;
    }
}

// Greg in transposed frequency layout: p = kc*NN + kr (verified R6)
__global__ void greg_k(const float* __restrict__ w, const float2* __restrict__ twN,
                       float* __restrict__ Greg) {
    int p = blockIdx.x * blockDim.x + threadIdx.x;
    if (p >= NP) return;
    int u = p % NN, v = p / NN;
    float2 rp[RK], cp[RK];
    for (int j = 0; j < RK; ++j) {
        int m = (u * (j - RK/2)) % NN; if (m < 0) m += NN;
        rp[j] = twN[m];
    }
    for (int k = 0; k < RK; ++k) {
        int m = (v * (k - RK/2)) % NN; if (m < 0) m += NN;
        cp[k] = twN[m];
    }
    float pr[RKT], pi[RKT];
    for (int j = 0; j < RK; ++j)
        for (int k = 0; k < RK; ++k) {
            pr[j*RK+k] = rp[j].x*cp[k].x - rp[j].y*cp[k].y;
            pi[j*RK+k] = rp[j].x*cp[k].y + rp[j].y*cp[k].x;
        }
    float acc = 0.f;
    for (int f = 0; f < NF; ++f) {
        float gr = 0.f, gi = 0.f;
        for (int i = 0; i < RKT; ++i) {
            float wv = w[f*RKT + i];
            gr += wv * pr[i];
            gi += wv * pi[i];
        }
        acc += gr*gr + gi*gi;
    }
    Greg[p] = acc;
}

// LDS-tiled border edgetaper.
// grid: (39, 24). bx<20: top/bottom row-quads (10 quads x 2 col halves).
//                 bx>=20: side chunks (19 chunks of 26 rows x 34 side cols).
// Conv written as contiguous-window correlation over an extended LDS tile:
//   out[r][c] = sum_{j,k} psf[j][k] * I[g(r-j)][g(c-k)]
// Each thread computes 4-5 adjacent outputs -> 5-6 aligned ds_read_b128 + 68-85 FMA per j-row.
__global__ __launch_bounds__(256)
void border2_k(const void* __restrict__ image, const int* __restrict__ flags,
               const float* __restrict__ psf_all,
               const float* __restrict__ A0_all, const float* __restrict__ A1_all,
               float* __restrict__ borderV) {
    __shared__ float4 S4[1440];           // 23040 B; tb uses 20x288 floats, side 42x84
    float* S = (float*)S4;
    int bp = blockIdx.y;                  // plane 0..23
    int b = bp / 3;
    long ofs = (long)bp * IMGP;
    int bf = flags[0];
    int t = threadIdx.x;
    const float* pw = psf_all + b*KT;
    int bx = blockIdx.x;

    if (bx < 20) {
        // ---------- top/bottom full rows ----------
        int q = bx >> 1, h = bx & 1;
        int r0;
        if (q < 4) r0 = 4*q;                    // 0,4,8,12
        else if (q == 4) r0 = 13;               // covers 13..16 (overlap ok)
        else if (q < 9) r0 = 511 + 4*(q-5);     // 511,515,519,523
        else r0 = 524;                          // covers 524..527
        int X0 = h * 264;
        // stage S[20][288]: S[i][xi] = I[g(r0-16+i)][g(X0+xi-16)]
        for (int idx = t; idx < 20*288; idx += 256) {
            int i = idx / 288, xi = idx - i*288;
            int x = X0 + xi;
            float v = 0.f;
            if (x < 544) {
                int sr = gmap(r0 - 16 + i);
                int sc = gmap(x - 16);
                v = ldx(image, ofs + (long)sr*IMG + sc, bf);
            }
            S[idx] = v;
        }
        __syncthreads();
        for (int g = t; g < 264; g += 256) {
            int rx = g / 66, cl = g - rx*66;
            int c0 = X0 + 4*cl;
            int x0 = 4*cl;                       // local ext offset
            float acc0 = 0.f, acc1 = 0.f, acc2 = 0.f, acc3 = 0.f;
            for (int j = 0; j < KH; ++j) {
                const float4* SjV = (const float4*)(S + (16 + rx - j)*288 + x0);
                float xv[20];
                #pragma unroll
                for (int qv = 0; qv < 5; ++qv) {
                    float4 tv = SjV[qv];
                    xv[4*qv+0] = tv.x; xv[4*qv+1] = tv.y;
                    xv[4*qv+2] = tv.z; xv[4*qv+3] = tv.w;
                }
                const float* wj = pw + j*KH;     // block-uniform -> s_load
                #pragma unroll
                for (int qq = 0; qq < 20; ++qq) {
                    {int k = 0 + 16 - qq; if (k >= 0 && k < KH) acc0 += wj[k]*xv[qq];}
                    {int k = 1 + 16 - qq; if (k >= 0 && k < KH) acc1 += wj[k]*xv[qq];}
                    {int k = 2 + 16 - qq; if (k >= 0 && k < KH) acc2 += wj[k]*xv[qq];}
                    {int k = 3 + 16 - qq; if (k >= 0 && k < KH) acc3 += wj[k]*xv[qq];}
                }
            }
            int r = r0 + rx;
            float a0v = A0_all[b*NN + r];
            int ibase = (r < 17) ? r*NN : TOPB + (r-511)*NN;
            float accs[4] = {acc0, acc1, acc2, acc3};
            #pragma unroll
            for (int d = 0; d < 4; ++d) {
                int c = c0 + d;
                float xo = S[(8 + rx)*288 + (x0 + 8 + d)];   // original padded pixel
                float al = a0v * A1_all[b*NN + c];
                borderV[(size_t)bp*BORD + ibase + c] = al*xo + (1.f - al)*accs[d];
            }
        }
    } else {
        // ---------- side columns (34 cols x 26 rows per block) ----------
        int chunk = bx - 20;
        int r0 = 17 + 26*chunk;                  // rows r0..r0+25, last = 510
        // stage S[42][84]: cols [0,33) = g(m), m=-16..16 ; cols [48,81) = g(m), m=495..527
        for (int idx = t; idx < 42*84; idx += 256) {
            int i = idx / 84, x = idx - i*84;
            float v = 0.f;
            int m = -1000;
            if (x < 33) m = x - 16;
            else if (x >= 48 && x < 81) m = x - 48 + 495;
            if (m != -1000) {
                int sr = gmap(r0 - 16 + i);
                int sc = gmap(m);
                v = ldx(image, ofs + (long)sr*IMG + sc, bf);
            }
            S[idx] = v;
        }
        __syncthreads();
        int g = t;
        if (g < 208) {
            int ry = g >> 3, s = g & 7;
            int c0 = (s < 4) ? 4*s : 511 + 4*(s-4);
            int sz = ((s & 3) == 3) ? 5 : 4;
            int x0 = (s < 4) ? 4*s : 48 + 4*(s-4);
            float acc0=0.f, acc1=0.f, acc2=0.f, acc3=0.f, acc4=0.f;
            for (int j = 0; j < KH; ++j) {
                const float4* SjV = (const float4*)(S + (16 + ry - j)*84 + x0);
                float xv[24];
                #pragma unroll
                for (int qv = 0; qv < 6; ++qv) {
                    float4 tv = SjV[qv];
                    xv[4*qv+0] = tv.x; xv[4*qv+1] = tv.y;
                    xv[4*qv+2] = tv.z; xv[4*qv+3] = tv.w;
                }
                const float* wj = pw + j*KH;
                #pragma unroll
                for (int qq = 0; qq < 21; ++qq) {
                    {int k = 0 + 16 - qq; if (k >= 0 && k < KH) acc0 += wj[k]*xv[qq];}
                    {int k = 1 + 16 - qq; if (k >= 0 && k < KH) acc1 += wj[k]*xv[qq];}
                    {int k = 2 + 16 - qq; if (k >= 0 && k < KH) acc2 += wj[k]*xv[qq];}
                    {int k = 3 + 16 - qq; if (k >= 0 && k < KH) acc3 += wj[k]*xv[qq];}
                    {int k = 4 + 16 - qq; if (k >= 0 && k < KH) acc4 += wj[k]*xv[qq];}
                }
            }
            int r = r0 + ry;
            float a0v = A0_all[b*NN + r];
            int cc0 = (s < 4) ? c0 : c0 - 494;
            size_t ib = (size_t)bp*BORD + ROWB + (size_t)(r-17)*34 + cc0;
            float accs[5] = {acc0, acc1, acc2, acc3, acc4};
            #pragma unroll
            for (int d = 0; d < 5; ++d) {
                if (d < sz) {
                    int c = c0 + d;
                    float xo = S[(8 + ry)*84 + (x0 + 8 + d)];
                    float al = a0v * A1_all[b*NN + c];
                    borderV[ib + d] = al*xo + (1.f - al)*accs[d];
                }
            }
        }
    }
}

// bulk pad+pack for 6 planes; border pixels read precomputed borderV
__global__ void pad6_k(const void* __restrict__ image, const int* __restrict__ flags,
                       const float* __restrict__ borderV,
                       float2* __restrict__ buf, int B0) {
    int idx = blockIdx.x * blockDim.x + threadIdx.x;
    if (idx >= 6*NP) return;
    int bf = flags[0];
    int q = idx / NP, p = idx % NP;
    int pair = q / 3, ch = q - 3*pair;
    int b0p = B0 + 2*pair;
    int r = p / NN, c = p % NN;
    float x0, x1;
    bool isb = (r < 17) | (r >= 511) | (c < 17) | (c >= 511);
    if (isb) {
        int i2;
        if (r < 17) i2 = r*NN + c;
        else if (r >= 511) i2 = TOPB + (r-511)*NN + c;
        else { int cc = (c < 17) ? c : c - 494; i2 = ROWB + (r-17)*34 + cc; }
        x0 = borderV[(size_t)(b0p*3 + ch)*BORD + i2];
        x1 = borderV[(size_t)((b0p+1)*3 + ch)*BORD + i2];
    } else {
        // interior: no mirroring possible (sr,sc in 9..502)
        long ofs0 = ((long)b0p*3 + ch) * IMGP + (long)(r - PAD)*IMG + (c - PAD);
        x0 = ldx(image, ofs0, bf);
        x1 = ldx(image, ofs0 + 3L*IMGP, bf);
    }
    buf[(size_t)q*NP + p] = make_float2(x0, x1);
}

// 1D FFT (528=16*33), one block per row; safe with in==out (full row staged in LDS)
__global__ __launch_bounds__(128)
void fft_pass(const float2* __restrict__ in, float2* __restrict__ out,
              const float2* __restrict__ twN, int inv) {
    __shared__ float2 X[NN];
    __shared__ float2 A[NN];
    __shared__ float2 TW[NN];
    int t = threadIdx.x;
    const float2* src = in + (size_t)blockIdx.x * NN;
    float2* dst = out + (size_t)blockIdx.x * NN;
    for (int i = t; i < NN; i += 128) { X[i] = src[i]; TW[i] = twN[i]; }
    __syncthreads();
    float s = inv ? -1.f : 1.f;
    for (int o = t; o < NN; o += 128) {
        int n1 = o & 15, k2 = o >> 4;
        float ar = 0.f, ai = 0.f;
        int m = 0;
        for (int n2 = 0; n2 < 33; ++n2) {
            float2 xv = X[n1 + 16*n2];
            float2 w = TW[m * 16];
            float wr = w.x, wi = w.y * s;
            ar += xv.x*wr - xv.y*wi;
            ai += xv.x*wi + xv.y*wr;
            m += k2; if (m >= 33) m -= 33;
        }
        float2 tw = TW[n1 * k2];
        float twr = tw.x, twi = tw.y * s;
        A[n1*33 + k2] = make_float2(ar*twr - ai*twi, ar*twi + ai*twr);
    }
    __syncthreads();
    for (int o = t; o < NN; o += 128) {
        int k1 = o / 33, k2 = o - 33*k1;
        float ar = 0.f, ai = 0.f;
        int m = 0;
        for (int n1 = 0; n1 < 16; ++n1) {
            float2 bv = A[n1*33 + k2];
            float2 w = TW[m * 33];
            float wr = w.x, wi = w.y * s;
            ar += bv.x*wr - bv.y*wi;
            ai += bv.x*wi + bv.y*wr;
            m = (m + k1) & 15;
        }
        dst[o] = make_float2(ar, ai);
    }
}

// in-place square transpose: tile-pair swap, 561 upper-tri tiles per plane
__global__ void transpose_ip_k(float2* __restrict__ buf) {
    int tnum = blockIdx.x;
    int ti = 0, rem = tnum;
    while (rem >= 33 - ti) { rem -= 33 - ti; ti++; }
    int tj = ti + rem;
    float2* pl = buf + (size_t)blockIdx.z * NP;
    __shared__ float2 ta[16][17], tb[16][17];
    int tx = threadIdx.x, ty = threadIdx.y;
    int ra = ti*16 + ty, ca = tj*16 + tx;
    int rb = tj*16 + ty, cb = ti*16 + tx;
    ta[ty][tx] = pl[(size_t)ra*NN + ca];
    tb[ty][tx] = pl[(size_t)rb*NN + cb];
    __syncthreads();
    pl[(size_t)ra*NN + ca] = tb[tx][ty];
    pl[(size_t)rb*NN + cb] = ta[tx][ty];
}

// column-sum factor S(b, v, j) = sum_k psf[b][j][k] * tw[v*(k-8)]  (u-independent part of K)
__global__ void kv_k(const float* __restrict__ psf_all, const float2* __restrict__ twN,
                     float2* __restrict__ Sv) {
    int idx = blockIdx.x * blockDim.x + threadIdx.x;
    if (idx >= 8*NN*KH) return;
    int j = idx % KH;
    int rest = idx / KH;
    int v = rest % NN, b = rest / NN;
    int m = (520 * v) % NN;   // (-8v) mod 528
    float sr = 0.f, si = 0.f;
    const float* ps = psf_all + b*KT + j*KH;
    for (int k = 0; k < KH; ++k) {
        float2 cp = twN[m];
        m += v; if (m >= NN) m -= NN;
        sr += ps[k] * cp.x;
        si += ps[k] * cp.y;
    }
    Sv[idx] = make_float2(sr, si);
}

// fused Wiener filter + Hermitian unpack/apply/repack, in-place; K via Sv factorization
__global__ __launch_bounds__(256)
void cmulw2_k(float2* __restrict__ buf, const float2* __restrict__ Sv,
              const float* __restrict__ Greg, const float2* __restrict__ twN,
              const float* __restrict__ alpha4, const float* __restrict__ wgt4, int B0) {
    int pair = blockIdx.y;
    int b0p = B0 + 2*pair;
    __shared__ float2 tw[NN];
    for (int i = threadIdx.x; i < NN; i += 256) tw[i] = twN[i];
    __syncthreads();
    int p = blockIdx.x * blockDim.x + threadIdx.x;
    if (p >= NP) return;
    int u = p % NN, v = p / NN;
    int um = (NN - u) % NN, vm = (NN - v) % NN;
    int pm = vm * NN + um;
    if (pm < p) return;
    const float2* S0 = Sv + ((size_t)(b0p    )*NN + v)*KH;
    const float2* S1 = Sv + ((size_t)(b0p + 1)*NN + v)*KH;
    int mu = (520 * u) % NN;
    float K0r = 0.f, K0i = 0.f, K1r = 0.f, K1i = 0.f;
    for (int j = 0; j < KH; ++j) {
        float2 rp = tw[mu]; mu += u; if (mu >= NN) mu -= NN;
        float2 s0 = S0[j], s1 = S1[j];
        K0r += rp.x*s0.x - rp.y*s0.y;  K0i += rp.x*s0.y + rp.y*s0.x;
        K1r += rp.x*s1.x - rp.y*s1.y;  K1i += rp.x*s1.y + rp.y*s1.x;
    }
    float g = Greg[p];
    float K20 = K0r*K0r + K0i*K0i;
    float K21 = K1r*K1r + K1i*K1i;
    float s0 = 0.f, s1 = 0.f;
    for (int d = 0; d < ND; ++d) {
        float a = __expf(alpha4[d]);
        float wd = wgt4[d];
        s0 += wd / fmaxf(K20 + a*g, 1e-30f);
        s1 += wd / fmaxf(K21 + a*g, 1e-30f);
    }
    s0 *= (1.f/(float)NP);
    s1 *= (1.f/(float)NP);
    float W0r = K0r*s0, W0i = -K0i*s0;
    float W1r = K1r*s1, W1i = -K1i*s1;
    float2* pl = buf + (size_t)pair*3*NP;
    for (int ch = 0; ch < 3; ++ch) {
        float2 Z  = pl[(size_t)ch*NP + p];
        float2 Zm = pl[(size_t)ch*NP + pm];
        float X0r = 0.5f*(Z.x + Zm.x), X0i = 0.5f*(Z.y - Zm.y);
        float X1r = 0.5f*(Z.y + Zm.y), X1i = 0.5f*(Zm.x - Z.x);
        float Y0r = X0r*W0r - X0i*W0i, Y0i = X0r*W0i + X0i*W0r;
        float Y1r = X1r*W1r - X1i*W1i, Y1i = X1r*W1i + X1i*W1r;
        pl[(size_t)ch*NP + p]  = make_float2(Y0r - Y1i, Y0i + Y1r);
        pl[(size_t)ch*NP + pm] = make_float2(Y0r + Y1i, Y1r - Y0i);
    }
}

// final inverse row-FFT fused with crop: computes only cols 8..519, writes fp32 out
__global__ __launch_bounds__(128)
void fft_crop_k(const float2* __restrict__ in, float* __restrict__ out,
                const float2* __restrict__ twN, int B0) {
    __shared__ float2 X[NN];
    __shared__ float2 A[NN];
    __shared__ float2 TW[NN];
    int t = threadIdx.x;
    int q = blockIdx.x >> 9;
    int rp = (blockIdx.x & 511) + PAD;
    int pair = q / 3, ch = q - 3*pair;
    int b0p = B0 + 2*pair;
    const float2* src = in + (size_t)q*NP + (size_t)rp*NN;
    for (int i = t; i < NN; i += 128) { X[i] = src[i]; TW[i] = twN[i]; }
    __syncthreads();
    const float s = -1.f;
    for (int o = t; o < NN; o += 128) {
        int n1 = o & 15, k2 = o >> 4;
        float ar = 0.f, ai = 0.f;
        int m = 0;
        for (int n2 = 0; n2 < 33; ++n2) {
            float2 xv = X[n1 + 16*n2];
            float2 w = TW[m * 16];
            float wr = w.x, wi = w.y * s;
            ar += xv.x*wr - xv.y*wi;
            ai += xv.x*wi + xv.y*wr;
            m += k2; if (m >= 33) m -= 33;
        }
        float2 tw = TW[n1 * k2];
        float twr = tw.x, twi = tw.y * s;
        A[n1*33 + k2] = make_float2(ar*twr - ai*twi, ar*twi + ai*twr);
    }
    __syncthreads();
    float* o0 = out + ((size_t)b0p*3 + ch) * IMGP + (size_t)(rp - PAD) * IMG;
    float* o1 = o0 + 3L*IMGP;
    for (int o = PAD + t; o < IMG + PAD; o += 128) {
        int k1 = o / 33, k2 = o - 33*k1;
        float ar = 0.f, ai = 0.f;
        int m = 0;
        for (int n1 = 0; n1 < 16; ++n1) {
            float2 bv = A[n1*33 + k2];
            float2 w = TW[m * 33];
            float wr = w.x, wi = w.y * s;
            ar += bv.x*wr - bv.y*wi;
            ai += bv.x*wi + bv.y*wr;
            m = (m + k1) & 15;
        }
        o0[o - PAD] = ar;
        o1[o - PAD] = ai;
    }
}

extern "C" void kernel_launch(void* const* d_in, const int* in_sizes, int n_in,
                              void* d_out, int out_size, void* d_ws, size_t ws_size,
                              hipStream_t stream) {
    int i_img = -1, i_bk = -1, i_wcw = -1, i_ws = -1, i_4a = -1, i_4b = -1;
    for (int i = 0; i < n_in; ++i) {
        int s = in_sizes[i];
        if (s == 8*3*IMG*IMG)   i_img = i;
        else if (s == 8*KT)     i_bk = i;
        else if (s == NF*RKT)   i_wcw = i;
        else if (s == NF)       i_ws = i;
        else if (s == ND) { if (i_4a < 0) i_4a = i; else i_4b = i; }
    }
    if (i_img < 0) i_img = 0;
    if (i_bk  < 0) i_bk  = 1;
    if (i_wcw < 0) i_wcw = 3;
    if (i_ws  < 0) i_ws  = 4;
    if (i_4a  < 0) i_4a  = 5;
    if (i_4b  < 0) i_4b  = i_4a;
    const void* image      = d_in[i_img];
    const void* blurKernel = d_in[i_bk];
    const void* wcw        = d_in[i_wcw];
    const void* wscale     = d_in[i_ws];
    const float* c4a       = (const float*)d_in[i_4a];
    const float* c4b       = (const float*)d_in[i_4b];
    float* out = (float*)d_out;

    char* base = (char*)d_ws;
    int*    flags    = (int*)(base);
    float*  alpha_ws = (float*)(base + 64);
    float*  wgt_ws   = (float*)(base + 80);
    float2* twN      = (float2*)(base + 256);
    float*  wnorm    = (float*)(base + 4480);
    float*  psf_all  = (float*)(base + 6880);
    float*  A0       = (float*)(base + 16128);
    float*  A1       = (float*)(base + 33024);
    float*  Greg     = (float*)(base + 49920);      // NP*4 = 1115136
    float2* buf      = (float2*)(base + 1165056);   // 6*NP*8 = 13381632
    float*  borderV  = (float*)(base + 14546688);   // 24*BORD*4 = 3335808
    float2* Sv       = (float2*)(base + 17882496);  // 8*NN*KH*8 = 574464 -> end 18456960

    if (ws_size < 18456960) return;

    detect_k<<<1, 64, 0, stream>>>(image, in_sizes[i_img], blurKernel, in_sizes[i_bk],
                                   wcw, in_sizes[i_wcw], wscale, in_sizes[i_ws],
                                   c4a, c4b, flags, alpha_ws, wgt_ws);
    twinit_k<<<(NN+63)/64, 64, 0, stream>>>(twN);
    wnorm_k<<<1, 64, 0, stream>>>(wcw, wscale, flags, wnorm);
    prep_k<<<8, 64, 0, stream>>>(blurKernel, flags, psf_all, A0, A1);
    greg_k<<<(NP+255)/256, 256, 0, stream>>>(wnorm, twN, Greg);
    kv_k<<<(8*NN*KH+255)/256, 256, 0, stream>>>(psf_all, twN, Sv);

    dim3 bgrid2(39, 24);
    border2_k<<<bgrid2, 256, 0, stream>>>(image, flags, psf_all, A0, A1, borderV);

    dim3 tblk(16, 16);
    dim3 tgrid6(561, 1, 6);
    dim3 cgrid((NP+255)/256, 2);

    for (int B0 = 0; B0 < 8; B0 += 4) {
        pad6_k<<<(6*NP+255)/256, 256, 0, stream>>>(image, flags, borderV, buf, B0);
        fft_pass<<<6*NN, 128, 0, stream>>>(buf, buf, twN, 0);        // rows fwd (in-place)
        transpose_ip_k<<<tgrid6, tblk, 0, stream>>>(buf);
        fft_pass<<<6*NN, 128, 0, stream>>>(buf, buf, twN, 0);        // cols fwd
        cmulw2_k<<<cgrid, 256, 0, stream>>>(buf, Sv, Greg, twN, alpha_ws, wgt_ws, B0);
        fft_pass<<<6*NN, 128, 0, stream>>>(buf, buf, twN, 1);        // cols inv
        transpose_ip_k<<<tgrid6, tblk, 0, stream>>>(buf);
        fft_crop_k<<<6*IMG, 128, 0, stream>>>(buf, out, twN, B0);    // rows inv + crop
    }
}